// Round 9
// baseline (400.250 us; speedup 1.0000x reference)
//
#include <hip/hip_runtime.h>
#include <math.h>

#define DIMC 64
#define NE 512
#define HWSZ 4096              // 64*64
#define NPTS 131072
#define DECAYF 0.99f
#define OMD 0.01f
#define EPSF 1e-5f
#define MARGIN 1e-3f
#define FCAP 16384

// output offsets (floats) — out0 is [32,64,64,64] = 8388608 elements
#define O0 0
#define O1 8388608                 // diff scalar
#define O2 8388609                 // embed_ind [32,64,64]
#define O3 8519681                 // new_cluster_size [512]
#define O4 8520193                 // new_dictionary_avg [64,512]
#define O5 8552961                 // new_dictionary [64,512]
#define O6 8585729                 // mean_D scalar

// ws float-offset layout
#define WS_DIFF   0
#define WS_ESUM   64                       // [c][j] 64*512 (reduced)
#define WS_COUNTS 32832                    // 512
#define WS_DT     33344                    // [j][c] dictT f32, 32768
#define WS_NORM   66112                    // 512: -0.5*||d_j||^2
#define WS_DHI    66624                    // 512x64 bf16 (16384 floats)
#define WS_DLO    83008                    // 512x64 bf16
#define WS_NFLAG  99392                    // 1 int
#define WS_FLIST  99393                    // FCAP ints
#define WS_BIDX   115777                   // NPTS ints
#define WS_PART   246852                   // NBLK x 33280 partials (16B aligned)
#define PART_STRIDE 33280
#define NBLK 256
#define WS_NEED_BYTES ((size_t)(WS_PART + (size_t)NBLK * PART_STRIDE) * 4)

typedef __attribute__((ext_vector_type(8))) short bf16x8;
typedef __attribute__((ext_vector_type(4))) float f32x4;

__device__ __forceinline__ unsigned bf16rne(float x) {
    unsigned u = __float_as_uint(x);
    return (u + 0x7FFFu + ((u >> 16) & 1u)) >> 16;
}

// -------- K1: dictT f32 + bf16 hi/lo split + negated half-norms --------
__global__ void k_prep(const float* __restrict__ dict, float* __restrict__ ws) {
    int j = blockIdx.x, c = threadIdx.x;
    float v = dict[c * NE + j];
    ws[WS_DT + j * DIMC + c] = v;
    unsigned h = bf16rne(v);
    float fh = __uint_as_float(h << 16);
    unsigned l = bf16rne(v - fh);
    ((unsigned short*)(ws + WS_DHI))[j * DIMC + c] = (unsigned short)h;
    ((unsigned short*)(ws + WS_DLO))[j * DIMC + c] = (unsigned short)l;
    float s = v * v;
    #pragma unroll
    for (int off = 32; off > 0; off >>= 1) s += __shfl_down(s, off);
    if (c == 0) ws[WS_NORM + j] = -0.5f * s;
}

#define MFMA16(A, B, C) __builtin_amdgcn_mfma_f32_16x16x32_bf16(A, B, C, 0, 0, 0)

// -------- K2a: MFMA scoring -> bidx (+flag list). No epilogue. --------
// 512 blocks x 256 threads (4 waves); wave computes 64 points x 512 codes.
__global__ __launch_bounds__(256, 2) void k_score(
        const float* __restrict__ x, float* __restrict__ ws) {
    extern __shared__ float lds[];
    char* ldsB = (char*)lds;           // hi[256][64]bf16 | lo  (64 KB)
    int*  bidxl = (int*)lds;           // reused after sweep (256 ints)

    const int tid  = threadIdx.x;
    const int lane = tid & 63;
    const int w    = tid >> 6;

    const int n0 = blockIdx.x * 256 + tid;
    const int b = n0 >> 12, hw0 = n0 & 4095;
    const float* xp = x + (size_t)b * (DIMC * HWSZ) + hw0;

    // ---- load point + bf16 split + stage to LDS (chunk-XOR swizzled) ----
    {
        float f0[DIMC];
        #pragma unroll
        for (int c = 0; c < DIMC; ++c) f0[c] = xp[c * HWSZ];
        unsigned hiw[32], low[32];
        #pragma unroll
        for (int i = 0; i < 32; ++i) {
            unsigned h0 = bf16rne(f0[2 * i]);
            unsigned h1 = bf16rne(f0[2 * i + 1]);
            float fh0 = __uint_as_float(h0 << 16);
            float fh1 = __uint_as_float(h1 << 16);
            unsigned l0 = bf16rne(f0[2 * i] - fh0);
            unsigned l1 = bf16rne(f0[2 * i + 1] - fh1);
            hiw[i] = h0 | (h1 << 16);
            low[i] = l0 | (l1 << 16);
        }
        const int swz = tid & 7;
        #pragma unroll
        for (int k = 0; k < 8; ++k) {
            uint4 vh = {hiw[4 * k], hiw[4 * k + 1], hiw[4 * k + 2], hiw[4 * k + 3]};
            uint4 vl = {low[4 * k], low[4 * k + 1], low[4 * k + 2], low[4 * k + 3]};
            *(uint4*)(ldsB + tid * 128 + ((k ^ swz) << 4)) = vh;
            *(uint4*)(ldsB + 32768 + tid * 128 + ((k ^ swz) << 4)) = vl;
        }
    }
    __syncthreads();

    // ---- A-fragments (row = lane&15, k = (lane>>4)*8 + e, +32*kk) ----
    bf16x8 ahi[4][2], alo[4][2];
    #pragma unroll
    for (int pt = 0; pt < 4; ++pt) {
        const int arow = (w << 6) + (pt << 4) + (lane & 15);
        const int swz = arow & 7;
        #pragma unroll
        for (int kk = 0; kk < 2; ++kk) {
            const int ch = (lane >> 4) + (kk << 2);
            ahi[pt][kk] = __builtin_bit_cast(bf16x8,
                *(const uint4*)(ldsB + arow * 128 + ((ch ^ swz) << 4)));
            alo[pt][kk] = __builtin_bit_cast(bf16x8,
                *(const uint4*)(ldsB + 32768 + arow * 128 + ((ch ^ swz) << 4)));
        }
    }
    __syncthreads();   // staging dead; lds reusable as bidxl

    // ---- MFMA sweep over 32 code-tiles ----
    const uint4* dh4 = (const uint4*)(ws + WS_DHI);
    const uint4* dl4 = (const uint4*)(ws + WS_DLO);
    const float* npl = ws + WS_NORM + (lane & 15);
    const int bl = ((lane & 15) << 3) + (lane >> 4);

    float best[4][4], sec[4][4];
    int   idx[4][4];
    #pragma unroll
    for (int pt = 0; pt < 4; ++pt)
        #pragma unroll
        for (int r = 0; r < 4; ++r) {
            best[pt][r] = -3.4e38f; sec[pt][r] = -3.4e38f; idx[pt][r] = 0;
        }

    #pragma unroll 2
    for (int jt = 0; jt < 32; ++jt) {
        uint4 uh0 = dh4[(jt << 7) + bl];
        uint4 uh1 = dh4[(jt << 7) + bl + 4];
        uint4 ul0 = dl4[(jt << 7) + bl];
        uint4 ul1 = dl4[(jt << 7) + bl + 4];
        float nrm = npl[jt << 4];
        bf16x8 bh0 = __builtin_bit_cast(bf16x8, uh0);
        bf16x8 bh1 = __builtin_bit_cast(bf16x8, uh1);
        bf16x8 bl0 = __builtin_bit_cast(bf16x8, ul0);
        bf16x8 bl1 = __builtin_bit_cast(bf16x8, ul1);
        const int jc = (jt << 4) + (lane & 15);
        #pragma unroll
        for (int pt = 0; pt < 4; ++pt) {
            f32x4 acc = {0.f, 0.f, 0.f, 0.f};
            acc = MFMA16(ahi[pt][0], bh0, acc);
            acc = MFMA16(ahi[pt][1], bh1, acc);
            acc = MFMA16(ahi[pt][0], bl0, acc);
            acc = MFMA16(ahi[pt][1], bl1, acc);
            acc = MFMA16(alo[pt][0], bh0, acc);
            acc = MFMA16(alo[pt][1], bh1, acc);
            acc = MFMA16(alo[pt][0], bl0, acc);
            acc = MFMA16(alo[pt][1], bl1, acc);
            #pragma unroll
            for (int r = 0; r < 4; ++r) {
                float s = acc[r] + nrm;
                bool gt = s > best[pt][r];
                float ns = gt ? best[pt][r] : (s > sec[pt][r] ? s : sec[pt][r]);
                best[pt][r] = gt ? s : best[pt][r];
                idx[pt][r]  = gt ? jc : idx[pt][r];
                sec[pt][r]  = ns;
            }
        }
    }

    // ---- argmax reduce across 16-lane code groups ----
    #pragma unroll
    for (int off = 8; off > 0; off >>= 1) {
        #pragma unroll
        for (int pt = 0; pt < 4; ++pt)
            #pragma unroll
            for (int r = 0; r < 4; ++r) {
                float ob = __shfl_xor(best[pt][r], off, 16);
                float os = __shfl_xor(sec[pt][r], off, 16);
                int   oi = __shfl_xor(idx[pt][r], off, 16);
                bool take = (ob > best[pt][r]) ||
                            (ob == best[pt][r] && oi < idx[pt][r]);
                float nsec = fmaxf(fminf(ob, best[pt][r]),
                                   fmaxf(os, sec[pt][r]));
                best[pt][r] = take ? ob : best[pt][r];
                idx[pt][r]  = take ? oi : idx[pt][r];
                sec[pt][r]  = nsec;
            }
    }
    if ((lane & 15) == 0) {
        const int g = lane >> 4;
        #pragma unroll
        for (int pt = 0; pt < 4; ++pt)
            #pragma unroll
            for (int r = 0; r < 4; ++r) {
                int p = (w << 6) + (pt << 4) + (g << 2) + r;
                int flag = (best[pt][r] - sec[pt][r] < MARGIN) ? 65536 : 0;
                bidxl[p] = idx[pt][r] | flag;
            }
    }
    __syncthreads();

    int ent = bidxl[tid];
    ((int*)ws)[WS_BIDX + n0] = ent & 511;
    if (ent & 65536) {
        int pos = atomicAdd((int*)ws + WS_NFLAG, 1);
        if (pos < FCAP) ((int*)ws)[WS_FLIST + pos] = n0;
    }
}

// -------- K2b: exact fp32 rescan of flagged points (4 threads/point) ----
// 256 blocks x 256 threads = 16384 points capacity (>= FCAP), one pass,
// early-exit beyond nf. launch_bounds(256,1): let f0[64]+rows live in VGPRs.
__global__ __launch_bounds__(256, 1) void k_fix(
        const float* __restrict__ x, float* __restrict__ ws) {
    int* iw = (int*)ws;
    int nf = iw[WS_NFLAG]; if (nf > FCAP) nf = FCAP;
    const int gid = blockIdx.x * 256 + threadIdx.x;
    const int i = gid >> 2, sub = gid & 3;
    if (i >= nf) return;

    const float* dptr = ws + WS_DT;
    const float* nptr = ws + WS_NORM;

    const int n = iw[WS_FLIST + i];
    const int b = n >> 12, hw = n & 4095;
    const float* xp = x + (size_t)b * (DIMC * HWSZ) + hw;
    float f0[DIMC];
    #pragma unroll
    for (int c = 0; c < DIMC; ++c) f0[c] = xp[c * HWSZ];

    float bb = -3.4e38f; int bj = 0;
    const int j0 = sub << 7;
    #pragma unroll 2
    for (int jj = 0; jj < 128; ++jj) {
        const int j = j0 + jj;
        const float4* row = (const float4*)(dptr + (size_t)j * DIMC);
        float a0 = 0.f, a1 = 0.f, a2 = 0.f, a3 = 0.f;
        #pragma unroll
        for (int c4 = 0; c4 < 16; ++c4) {
            float4 r4 = row[c4];
            const int cb = 4 * c4;
            a0 = fmaf(r4.x, f0[cb + 0], a0);
            a1 = fmaf(r4.y, f0[cb + 1], a1);
            a2 = fmaf(r4.z, f0[cb + 2], a2);
            a3 = fmaf(r4.w, f0[cb + 3], a3);
        }
        float sc = ((a0 + a1) + (a2 + a3)) + nptr[j];
        if (sc > bb) { bb = sc; bj = j; }
    }
    // order-preserving merge across the 4 sub-chunks
    #pragma unroll
    for (int off = 1; off < 4; off <<= 1) {
        float ob = __shfl_xor(bb, off, 4);
        int   oi = __shfl_xor(bj, off, 4);
        bool take = (ob > bb) || (ob == bb && oi < bj);
        bb = take ? ob : bb;
        bj = take ? oi : bj;
    }
    if (sub == 0) iw[WS_BIDX + n] = bj;
}

// -------- K2c: gather/quantize/stats from final bidx --------
__global__ __launch_bounds__(512, 1) void k_emit(
        const float* __restrict__ x, float* __restrict__ ws,
        float* __restrict__ out, int use_part) {
    extern __shared__ float lds[];
    float* esum  = lds;                 // 32768: esum_t [c][j]
    int*   lhist = (int*)(lds + 32768); // 512
    float* lred  = lds + 33280;         // 8

    const int tid = threadIdx.x;
    {
        float4 z = {0.f, 0.f, 0.f, 0.f};
        float4* e4 = (float4*)esum;
        #pragma unroll
        for (int k = 0; k < 16; ++k) e4[tid + 512 * k] = z;
        lhist[tid] = 0;
    }
    __syncthreads();

    const int n0 = blockIdx.x * 512 + tid;
    const int b = n0 >> 12, hw0 = n0 & 4095;
    const float* xp = x + (size_t)b * (DIMC * HWSZ) + hw0;
    float f0[DIMC];
    #pragma unroll
    for (int c = 0; c < DIMC; ++c) f0[c] = xp[c * HWSZ];

    const int bi0 = ((const int*)ws)[WS_BIDX + n0];
    atomicAdd(&lhist[bi0], 1);
    out[O2 + n0] = (float)bi0;

    const float* dptr = ws + WS_DT;
    float ssum = 0.f;
    float* o0 = out + O0 + (size_t)b * (DIMC * HWSZ) + hw0;
    const float4* q40 = (const float4*)(dptr + (size_t)bi0 * DIMC);
    #pragma unroll
    for (int c4 = 0; c4 < 16; ++c4) {
        float4 qa = q40[c4];
        const int cb = 4 * c4;
        o0[(cb + 0) * HWSZ] = qa.x;
        o0[(cb + 1) * HWSZ] = qa.y;
        o0[(cb + 2) * HWSZ] = qa.z;
        o0[(cb + 3) * HWSZ] = qa.w;
        float d;
        d = qa.x - f0[cb + 0]; ssum = fmaf(d, d, ssum);
        d = qa.y - f0[cb + 1]; ssum = fmaf(d, d, ssum);
        d = qa.z - f0[cb + 2]; ssum = fmaf(d, d, ssum);
        d = qa.w - f0[cb + 3]; ssum = fmaf(d, d, ssum);
    }

    #pragma unroll
    for (int c = 0; c < DIMC; ++c) atomicAdd(&esum[c * NE + bi0], f0[c]);
    __syncthreads();

    if (use_part) {
        float* part = ws + WS_PART + (size_t)blockIdx.x * PART_STRIDE;
        float4* p4 = (float4*)part;
        const float4* e4 = (const float4*)esum;
        #pragma unroll
        for (int k = 0; k < 16; ++k) p4[tid + 512 * k] = e4[tid + 512 * k];
        part[32768 + tid] = (float)lhist[tid];
    } else {
        #pragma unroll
        for (int k = 0; k < 64; ++k)
            atomicAdd(&ws[WS_ESUM + tid + 512 * k], esum[tid + 512 * k]);
        atomicAdd(&ws[WS_COUNTS + tid], (float)lhist[tid]);
    }

    #pragma unroll
    for (int off = 32; off > 0; off >>= 1) ssum += __shfl_down(ssum, off);
    if ((tid & 63) == 0) lred[tid >> 6] = ssum;
    __syncthreads();
    if (tid == 0) {
        float t = 0.f;
        #pragma unroll
        for (int w2 = 0; w2 < 8; ++w2) t += lred[w2];
        atomicAdd(ws + WS_DIFF, t);
    }
}

// -------- K2d: tree-reduce per-block partials --------
__global__ void k_reduce(float* __restrict__ ws) {
    const int gid = blockIdx.x * 128 + threadIdx.x;   // [0, 8320)
    const float4* src = (const float4*)(ws + WS_PART);
    float4 acc = {0.f, 0.f, 0.f, 0.f};
    #pragma unroll 4
    for (int p = 0; p < NBLK; ++p) {
        float4 v = src[(size_t)p * (PART_STRIDE / 4) + gid];
        acc.x += v.x; acc.y += v.y; acc.z += v.z; acc.w += v.w;
    }
    ((float4*)(ws + WS_ESUM))[gid] = acc;
}

// -------- K3: finalize EMA buffers / outputs --------
__global__ void k_final(const float* __restrict__ ws,
                        const float* __restrict__ cluster_size,
                        const float* __restrict__ davg,
                        float* __restrict__ out) {
    __shared__ float red[16];
    __shared__ float nsh;
    const int j = threadIdx.x;

    float cnt = ws[WS_COUNTS + j];
    float ncs = DECAYF * cluster_size[j] + OMD * cnt;
    out[O3 + j] = ncs;

    float v = ncs;
    #pragma unroll
    for (int off = 32; off > 0; off >>= 1) v += __shfl_down(v, off);
    if ((j & 63) == 0) red[j >> 6] = v;
    __syncthreads();
    if (j == 0) {
        float t = 0.f;
        #pragma unroll
        for (int w = 0; w < 8; ++w) t += red[w];
        nsh = t;
    }
    __syncthreads();
    const float n = nsh;
    const float csj = (ncs + EPSF) / (n + NE * EPSF) * n;

    float asum = 0.f;
    #pragma unroll
    for (int c = 0; c < DIMC; ++c) {
        float es = ws[WS_ESUM + c * NE + j];
        float da = davg[c * NE + j];
        float nda = DECAYF * da + OMD * es;
        out[O4 + c * NE + j] = nda;
        float nd = nda / csj;
        out[O5 + c * NE + j] = nd;
        asum += fabsf(nd);
    }

    __syncthreads();
    #pragma unroll
    for (int off = 32; off > 0; off >>= 1) asum += __shfl_down(asum, off);
    if ((j & 63) == 0) red[j >> 6] = asum;
    __syncthreads();
    if (j == 0) {
        float t = 0.f;
        #pragma unroll
        for (int w = 0; w < 8; ++w) t += red[w];
        out[O6] = t / 32768.0f;
        out[O1] = ws[WS_DIFF] / 8388608.0f;
    }
}

extern "C" void kernel_launch(void* const* d_in, const int* in_sizes, int n_in,
                              void* d_out, int out_size, void* d_ws, size_t ws_size,
                              hipStream_t stream) {
    const float* x    = (const float*)d_in[0];
    const float* dict = (const float*)d_in[1];
    const float* csz  = (const float*)d_in[2];
    const float* davg = (const float*)d_in[3];
    float* out = (float*)d_out;
    float* ws  = (float*)d_ws;

    const int use_part = (ws_size >= WS_NEED_BYTES) ? 1 : 0;

    hipMemsetAsync(ws, 0, (size_t)(WS_COUNTS + 512) * sizeof(float), stream);
    hipMemsetAsync(ws + WS_NFLAG, 0, sizeof(int), stream);

    k_prep<<<512, 64, 0, stream>>>(dict, ws);

    const int score_lds = 65536;
    hipFuncSetAttribute((const void*)k_score,
                        hipFuncAttributeMaxDynamicSharedMemorySize, score_lds);
    k_score<<<512, 256, score_lds, stream>>>(x, ws);

    k_fix<<<256, 256, 0, stream>>>(x, ws);

    const int emit_lds = 33288 * 4;
    hipFuncSetAttribute((const void*)k_emit,
                        hipFuncAttributeMaxDynamicSharedMemorySize, emit_lds);
    k_emit<<<NBLK, 512, emit_lds, stream>>>(x, ws, out, use_part);

    if (use_part) k_reduce<<<65, 128, 0, stream>>>(ws);

    k_final<<<1, 512, 0, stream>>>(ws, csz, davg, out);
}

// Round 10
// 175.328 us; speedup vs baseline: 2.2829x; 2.2829x over previous
//
#include <hip/hip_runtime.h>
#include <math.h>

#define DIMC 64
#define NE 512
#define HWSZ 4096              // 64*64
#define NPTS 131072
#define DECAYF 0.99f
#define OMD 0.01f
#define EPSF 1e-5f
#define MARGIN 1e-3f
#define FCAP 16384

// output offsets (floats) — out0 is [32,64,64,64] = 8388608 elements
#define O0 0
#define O1 8388608                 // diff scalar
#define O2 8388609                 // embed_ind [32,64,64]
#define O3 8519681                 // new_cluster_size [512]
#define O4 8520193                 // new_dictionary_avg [64,512]
#define O5 8552961                 // new_dictionary [64,512]
#define O6 8585729                 // mean_D scalar

// ws float-offset layout
#define WS_DIFF   0
#define WS_ESUM   64                       // [c][j] 64*512 (reduced)
#define WS_COUNTS 32832                    // 512
#define WS_DT     33344                    // [j][c] dictT f32, 32768
#define WS_NORM   66112                    // 512: -0.5*||d_j||^2
#define WS_DHI    66624                    // 512x64 bf16 (16384 floats)
#define WS_DLO    83008                    // 512x64 bf16
#define WS_NFLAG  99392                    // 1 int
#define WS_FLIST  99393                    // FCAP ints
#define WS_BIDX   115777                   // NPTS ints
#define WS_PART   246852                   // NBLK x 33280 partials (16B aligned)
#define PART_STRIDE 33280
#define NBLK 256
#define WS_NEED_BYTES ((size_t)(WS_PART + (size_t)NBLK * PART_STRIDE) * 4)

typedef __attribute__((ext_vector_type(8))) short bf16x8;
typedef __attribute__((ext_vector_type(4))) float f32x4;

__device__ __forceinline__ unsigned bf16rne(float x) {
    unsigned u = __float_as_uint(x);
    return (u + 0x7FFFu + ((u >> 16) & 1u)) >> 16;
}

// -------- K1: dictT f32 + bf16 hi/lo split + negated half-norms --------
__global__ void k_prep(const float* __restrict__ dict, float* __restrict__ ws) {
    int j = blockIdx.x, c = threadIdx.x;
    float v = dict[c * NE + j];
    ws[WS_DT + j * DIMC + c] = v;
    unsigned h = bf16rne(v);
    float fh = __uint_as_float(h << 16);
    unsigned l = bf16rne(v - fh);
    ((unsigned short*)(ws + WS_DHI))[j * DIMC + c] = (unsigned short)h;
    ((unsigned short*)(ws + WS_DLO))[j * DIMC + c] = (unsigned short)l;
    float s = v * v;
    #pragma unroll
    for (int off = 32; off > 0; off >>= 1) s += __shfl_down(s, off);
    if (c == 0) ws[WS_NORM + j] = -0.5f * s;
}

#define MFMA16(A, B, C) __builtin_amdgcn_mfma_f32_16x16x32_bf16(A, B, C, 0, 0, 0)

// -------- K2a: MFMA scoring -> bidx (+flag list). No epilogue. --------
// 512 blocks x 256 threads (4 waves); wave computes 64 points x 512 codes.
__global__ __launch_bounds__(256, 2) void k_score(
        const float* __restrict__ x, float* __restrict__ ws) {
    extern __shared__ float lds[];
    char* ldsB = (char*)lds;           // hi[256][64]bf16 | lo  (64 KB)
    int*  bidxl = (int*)lds;           // reused after sweep (256 ints)

    const int tid  = threadIdx.x;
    const int lane = tid & 63;
    const int w    = tid >> 6;

    const int n0 = blockIdx.x * 256 + tid;
    const int b = n0 >> 12, hw0 = n0 & 4095;
    const float* xp = x + (size_t)b * (DIMC * HWSZ) + hw0;

    // ---- load point + bf16 split + stage to LDS (chunk-XOR swizzled) ----
    {
        float f0[DIMC];
        #pragma unroll
        for (int c = 0; c < DIMC; ++c) f0[c] = xp[c * HWSZ];
        unsigned hiw[32], low[32];
        #pragma unroll
        for (int i = 0; i < 32; ++i) {
            unsigned h0 = bf16rne(f0[2 * i]);
            unsigned h1 = bf16rne(f0[2 * i + 1]);
            float fh0 = __uint_as_float(h0 << 16);
            float fh1 = __uint_as_float(h1 << 16);
            unsigned l0 = bf16rne(f0[2 * i] - fh0);
            unsigned l1 = bf16rne(f0[2 * i + 1] - fh1);
            hiw[i] = h0 | (h1 << 16);
            low[i] = l0 | (l1 << 16);
        }
        const int swz = tid & 7;
        #pragma unroll
        for (int k = 0; k < 8; ++k) {
            uint4 vh = {hiw[4 * k], hiw[4 * k + 1], hiw[4 * k + 2], hiw[4 * k + 3]};
            uint4 vl = {low[4 * k], low[4 * k + 1], low[4 * k + 2], low[4 * k + 3]};
            *(uint4*)(ldsB + tid * 128 + ((k ^ swz) << 4)) = vh;
            *(uint4*)(ldsB + 32768 + tid * 128 + ((k ^ swz) << 4)) = vl;
        }
    }
    __syncthreads();

    // ---- A-fragments (row = lane&15, k = (lane>>4)*8 + e, +32*kk) ----
    bf16x8 ahi[4][2], alo[4][2];
    #pragma unroll
    for (int pt = 0; pt < 4; ++pt) {
        const int arow = (w << 6) + (pt << 4) + (lane & 15);
        const int swz = arow & 7;
        #pragma unroll
        for (int kk = 0; kk < 2; ++kk) {
            const int ch = (lane >> 4) + (kk << 2);
            ahi[pt][kk] = __builtin_bit_cast(bf16x8,
                *(const uint4*)(ldsB + arow * 128 + ((ch ^ swz) << 4)));
            alo[pt][kk] = __builtin_bit_cast(bf16x8,
                *(const uint4*)(ldsB + 32768 + arow * 128 + ((ch ^ swz) << 4)));
        }
    }
    __syncthreads();   // staging dead; lds reusable as bidxl

    // ---- MFMA sweep over 32 code-tiles ----
    const uint4* dh4 = (const uint4*)(ws + WS_DHI);
    const uint4* dl4 = (const uint4*)(ws + WS_DLO);
    const float* npl = ws + WS_NORM + (lane & 15);
    const int bl = ((lane & 15) << 3) + (lane >> 4);

    float best[4][4], sec[4][4];
    int   idx[4][4];
    #pragma unroll
    for (int pt = 0; pt < 4; ++pt)
        #pragma unroll
        for (int r = 0; r < 4; ++r) {
            best[pt][r] = -3.4e38f; sec[pt][r] = -3.4e38f; idx[pt][r] = 0;
        }

    #pragma unroll 2
    for (int jt = 0; jt < 32; ++jt) {
        uint4 uh0 = dh4[(jt << 7) + bl];
        uint4 uh1 = dh4[(jt << 7) + bl + 4];
        uint4 ul0 = dl4[(jt << 7) + bl];
        uint4 ul1 = dl4[(jt << 7) + bl + 4];
        float nrm = npl[jt << 4];
        bf16x8 bh0 = __builtin_bit_cast(bf16x8, uh0);
        bf16x8 bh1 = __builtin_bit_cast(bf16x8, uh1);
        bf16x8 bl0 = __builtin_bit_cast(bf16x8, ul0);
        bf16x8 bl1 = __builtin_bit_cast(bf16x8, ul1);
        const int jc = (jt << 4) + (lane & 15);
        #pragma unroll
        for (int pt = 0; pt < 4; ++pt) {
            f32x4 acc = {0.f, 0.f, 0.f, 0.f};
            acc = MFMA16(ahi[pt][0], bh0, acc);
            acc = MFMA16(ahi[pt][1], bh1, acc);
            acc = MFMA16(ahi[pt][0], bl0, acc);
            acc = MFMA16(ahi[pt][1], bl1, acc);
            acc = MFMA16(alo[pt][0], bh0, acc);
            acc = MFMA16(alo[pt][1], bh1, acc);
            acc = MFMA16(alo[pt][0], bl0, acc);
            acc = MFMA16(alo[pt][1], bl1, acc);
            #pragma unroll
            for (int r = 0; r < 4; ++r) {
                float s = acc[r] + nrm;
                bool gt = s > best[pt][r];
                float ns = gt ? best[pt][r] : (s > sec[pt][r] ? s : sec[pt][r]);
                best[pt][r] = gt ? s : best[pt][r];
                idx[pt][r]  = gt ? jc : idx[pt][r];
                sec[pt][r]  = ns;
            }
        }
    }

    // ---- argmax reduce across 16-lane code groups ----
    #pragma unroll
    for (int off = 8; off > 0; off >>= 1) {
        #pragma unroll
        for (int pt = 0; pt < 4; ++pt)
            #pragma unroll
            for (int r = 0; r < 4; ++r) {
                float ob = __shfl_xor(best[pt][r], off, 16);
                float os = __shfl_xor(sec[pt][r], off, 16);
                int   oi = __shfl_xor(idx[pt][r], off, 16);
                bool take = (ob > best[pt][r]) ||
                            (ob == best[pt][r] && oi < idx[pt][r]);
                float nsec = fmaxf(fminf(ob, best[pt][r]),
                                   fmaxf(os, sec[pt][r]));
                best[pt][r] = take ? ob : best[pt][r];
                idx[pt][r]  = take ? oi : idx[pt][r];
                sec[pt][r]  = nsec;
            }
    }
    if ((lane & 15) == 0) {
        const int g = lane >> 4;
        #pragma unroll
        for (int pt = 0; pt < 4; ++pt)
            #pragma unroll
            for (int r = 0; r < 4; ++r) {
                int p = (w << 6) + (pt << 4) + (g << 2) + r;
                int flag = (best[pt][r] - sec[pt][r] < MARGIN) ? 65536 : 0;
                bidxl[p] = idx[pt][r] | flag;
            }
    }
    __syncthreads();

    int ent = bidxl[tid];
    ((int*)ws)[WS_BIDX + n0] = ent & 511;
    if (ent & 65536) {
        int pos = atomicAdd((int*)ws + WS_NFLAG, 1);
        if (pos < FCAP) ((int*)ws)[WS_FLIST + pos] = n0;
    }
}

// -------- K2b: exact fp32 rescan, ONE WAVE PER FLAGGED POINT --------
// Lane c holds x value for dim c (1 VGPR); f0[c] obtained via readlane
// (__shfl with constant index). Each lane scans 8 contiguous codes with
// the bit-identical quad fmaf chain; order-preserving butterfly merge.
__global__ __launch_bounds__(256, 2) void k_fix(
        const float* __restrict__ x, float* __restrict__ ws) {
    int* iw = (int*)ws;
    int nf = iw[WS_NFLAG]; if (nf > FCAP) nf = FCAP;
    const int tid = threadIdx.x;
    const int lane = tid & 63, w = tid >> 6;
    const int gw = blockIdx.x * 4 + w;      // global wave id
    const int nw = gridDim.x * 4;

    const float* dptr = ws + WS_DT;
    const float* nptr = ws + WS_NORM;

    for (int i = gw; i < nf; i += nw) {     // wave-uniform loop
        const int n = iw[WS_FLIST + i];
        const int b = n >> 12, hw = n & 4095;
        const float myf = x[(size_t)b * (DIMC * HWSZ) + (size_t)lane * HWSZ + hw];

        float bb = -3.4e38f; int bj = 0;
        #pragma unroll 2
        for (int s = 0; s < 8; ++s) {
            const int j = (lane << 3) + s;
            const float4* row = (const float4*)(dptr + (size_t)j * DIMC);
            float a0 = 0.f, a1 = 0.f, a2 = 0.f, a3 = 0.f;
            #pragma unroll
            for (int c4 = 0; c4 < 16; ++c4) {
                float4 r4 = row[c4];
                a0 = fmaf(r4.x, __shfl(myf, 4 * c4 + 0), a0);
                a1 = fmaf(r4.y, __shfl(myf, 4 * c4 + 1), a1);
                a2 = fmaf(r4.z, __shfl(myf, 4 * c4 + 2), a2);
                a3 = fmaf(r4.w, __shfl(myf, 4 * c4 + 3), a3);
            }
            float sc = ((a0 + a1) + (a2 + a3)) + nptr[j];
            if (sc > bb) { bb = sc; bj = j; }   // keeps lowest index (s ascending)
        }
        // order-preserving butterfly merge across 64 lanes
        #pragma unroll
        for (int off = 1; off < 64; off <<= 1) {
            float ob = __shfl_xor(bb, off);
            int   oi = __shfl_xor(bj, off);
            bool take = (ob > bb) || (ob == bb && oi < bj);
            bb = take ? ob : bb;
            bj = take ? oi : bj;
        }
        if (lane == 0) iw[WS_BIDX + n] = bj;
    }
}

// -------- K2c: gather/quantize/stats from final bidx --------
__global__ __launch_bounds__(512, 1) void k_emit(
        const float* __restrict__ x, float* __restrict__ ws,
        float* __restrict__ out, int use_part) {
    extern __shared__ float lds[];
    float* esum  = lds;                 // 32768: esum_t [c][j]
    int*   lhist = (int*)(lds + 32768); // 512
    float* lred  = lds + 33280;         // 8

    const int tid = threadIdx.x;
    {
        float4 z = {0.f, 0.f, 0.f, 0.f};
        float4* e4 = (float4*)esum;
        #pragma unroll
        for (int k = 0; k < 16; ++k) e4[tid + 512 * k] = z;
        lhist[tid] = 0;
    }
    __syncthreads();

    const int n0 = blockIdx.x * 512 + tid;
    const int b = n0 >> 12, hw0 = n0 & 4095;
    const float* xp = x + (size_t)b * (DIMC * HWSZ) + hw0;
    float f0[DIMC];
    #pragma unroll
    for (int c = 0; c < DIMC; ++c) f0[c] = xp[c * HWSZ];

    const int bi0 = ((const int*)ws)[WS_BIDX + n0];
    atomicAdd(&lhist[bi0], 1);
    out[O2 + n0] = (float)bi0;

    const float* dptr = ws + WS_DT;
    float ssum = 0.f;
    float* o0 = out + O0 + (size_t)b * (DIMC * HWSZ) + hw0;
    const float4* q40 = (const float4*)(dptr + (size_t)bi0 * DIMC);
    #pragma unroll
    for (int c4 = 0; c4 < 16; ++c4) {
        float4 qa = q40[c4];
        const int cb = 4 * c4;
        o0[(cb + 0) * HWSZ] = qa.x;
        o0[(cb + 1) * HWSZ] = qa.y;
        o0[(cb + 2) * HWSZ] = qa.z;
        o0[(cb + 3) * HWSZ] = qa.w;
        float d;
        d = qa.x - f0[cb + 0]; ssum = fmaf(d, d, ssum);
        d = qa.y - f0[cb + 1]; ssum = fmaf(d, d, ssum);
        d = qa.z - f0[cb + 2]; ssum = fmaf(d, d, ssum);
        d = qa.w - f0[cb + 3]; ssum = fmaf(d, d, ssum);
    }

    #pragma unroll
    for (int c = 0; c < DIMC; ++c) atomicAdd(&esum[c * NE + bi0], f0[c]);
    __syncthreads();

    if (use_part) {
        float* part = ws + WS_PART + (size_t)blockIdx.x * PART_STRIDE;
        float4* p4 = (float4*)part;
        const float4* e4 = (const float4*)esum;
        #pragma unroll
        for (int k = 0; k < 16; ++k) p4[tid + 512 * k] = e4[tid + 512 * k];
        part[32768 + tid] = (float)lhist[tid];
    } else {
        #pragma unroll
        for (int k = 0; k < 64; ++k)
            atomicAdd(&ws[WS_ESUM + tid + 512 * k], esum[tid + 512 * k]);
        atomicAdd(&ws[WS_COUNTS + tid], (float)lhist[tid]);
    }

    #pragma unroll
    for (int off = 32; off > 0; off >>= 1) ssum += __shfl_down(ssum, off);
    if ((tid & 63) == 0) lred[tid >> 6] = ssum;
    __syncthreads();
    if (tid == 0) {
        float t = 0.f;
        #pragma unroll
        for (int w2 = 0; w2 < 8; ++w2) t += lred[w2];
        atomicAdd(ws + WS_DIFF, t);
    }
}

// -------- K2d: tree-reduce per-block partials --------
__global__ void k_reduce(float* __restrict__ ws) {
    const int gid = blockIdx.x * 128 + threadIdx.x;   // [0, 8320)
    const float4* src = (const float4*)(ws + WS_PART);
    float4 acc = {0.f, 0.f, 0.f, 0.f};
    #pragma unroll 4
    for (int p = 0; p < NBLK; ++p) {
        float4 v = src[(size_t)p * (PART_STRIDE / 4) + gid];
        acc.x += v.x; acc.y += v.y; acc.z += v.z; acc.w += v.w;
    }
    ((float4*)(ws + WS_ESUM))[gid] = acc;
}

// -------- K3: finalize EMA buffers / outputs --------
__global__ void k_final(const float* __restrict__ ws,
                        const float* __restrict__ cluster_size,
                        const float* __restrict__ davg,
                        float* __restrict__ out) {
    __shared__ float red[16];
    __shared__ float nsh;
    const int j = threadIdx.x;

    float cnt = ws[WS_COUNTS + j];
    float ncs = DECAYF * cluster_size[j] + OMD * cnt;
    out[O3 + j] = ncs;

    float v = ncs;
    #pragma unroll
    for (int off = 32; off > 0; off >>= 1) v += __shfl_down(v, off);
    if ((j & 63) == 0) red[j >> 6] = v;
    __syncthreads();
    if (j == 0) {
        float t = 0.f;
        #pragma unroll
        for (int w = 0; w < 8; ++w) t += red[w];
        nsh = t;
    }
    __syncthreads();
    const float n = nsh;
    const float csj = (ncs + EPSF) / (n + NE * EPSF) * n;

    float asum = 0.f;
    #pragma unroll
    for (int c = 0; c < DIMC; ++c) {
        float es = ws[WS_ESUM + c * NE + j];
        float da = davg[c * NE + j];
        float nda = DECAYF * da + OMD * es;
        out[O4 + c * NE + j] = nda;
        float nd = nda / csj;
        out[O5 + c * NE + j] = nd;
        asum += fabsf(nd);
    }

    __syncthreads();
    #pragma unroll
    for (int off = 32; off > 0; off >>= 1) asum += __shfl_down(asum, off);
    if ((j & 63) == 0) red[j >> 6] = asum;
    __syncthreads();
    if (j == 0) {
        float t = 0.f;
        #pragma unroll
        for (int w = 0; w < 8; ++w) t += red[w];
        out[O6] = t / 32768.0f;
        out[O1] = ws[WS_DIFF] / 8388608.0f;
    }
}

extern "C" void kernel_launch(void* const* d_in, const int* in_sizes, int n_in,
                              void* d_out, int out_size, void* d_ws, size_t ws_size,
                              hipStream_t stream) {
    const float* x    = (const float*)d_in[0];
    const float* dict = (const float*)d_in[1];
    const float* csz  = (const float*)d_in[2];
    const float* davg = (const float*)d_in[3];
    float* out = (float*)d_out;
    float* ws  = (float*)d_ws;

    const int use_part = (ws_size >= WS_NEED_BYTES) ? 1 : 0;

    hipMemsetAsync(ws, 0, (size_t)(WS_COUNTS + 512) * sizeof(float), stream);
    hipMemsetAsync(ws + WS_NFLAG, 0, sizeof(int), stream);

    k_prep<<<512, 64, 0, stream>>>(dict, ws);

    const int score_lds = 65536;
    hipFuncSetAttribute((const void*)k_score,
                        hipFuncAttributeMaxDynamicSharedMemorySize, score_lds);
    k_score<<<512, 256, score_lds, stream>>>(x, ws);

    k_fix<<<256, 256, 0, stream>>>(x, ws);

    const int emit_lds = 33288 * 4;
    hipFuncSetAttribute((const void*)k_emit,
                        hipFuncAttributeMaxDynamicSharedMemorySize, emit_lds);
    k_emit<<<NBLK, 512, emit_lds, stream>>>(x, ws, out, use_part);

    if (use_part) k_reduce<<<65, 128, 0, stream>>>(ws);

    k_final<<<1, 512, 0, stream>>>(ws, csz, davg, out);
}

// Round 11
// 168.081 us; speedup vs baseline: 2.3813x; 1.0431x over previous
//
#include <hip/hip_runtime.h>
#include <math.h>

#define DIMC 64
#define NE 512
#define HWSZ 4096              // 64*64
#define NPTS 131072
#define DECAYF 0.99f
#define OMD 0.01f
#define EPSF 1e-5f
#define MARGIN 1e-3f
#define FCAP 16384
#define CCAP 8191

// output offsets (floats) — out0 is [32,64,64,64] = 8388608 elements
#define O0 0
#define O1 8388608                 // diff scalar
#define O2 8388609                 // embed_ind [32,64,64]
#define O3 8519681                 // new_cluster_size [512]
#define O4 8520193                 // new_dictionary_avg [64,512]
#define O5 8552961                 // new_dictionary [64,512]
#define O6 8585729                 // mean_D scalar

// ws float-offset layout
#define WS_DIFF   0
#define WS_ESUM   64                       // [c][j] 64*512 (reduced)
#define WS_COUNTS 32832                    // 512
#define WS_DT     33344                    // [j][c] dictT f32, 32768
#define WS_NORM   66112                    // 512: -0.5*||d_j||^2
#define WS_DHI    66624                    // 512x64 bf16; REUSED post-fused as CLIST
#define WS_DLO    83008                    // 512x64 bf16
#define WS_NFLAG  99392                    // 1 int
#define WS_FLIST  99393                    // FCAP ints
#define WS_BIDX   115777                   // NPTS ints
#define WS_CHG    246849                   // 1 int (spare gap before WS_PART)
#define WS_PART   246852                   // NBLK x 33280 partials (16B aligned)
#define PART_STRIDE 33280
#define NBLK 256
#define WS_NEED_BYTES ((size_t)(WS_PART + (size_t)NBLK * PART_STRIDE) * 4)
// change-list overlays WS_DHI (dead after fused kernel within a replay)
#define WS_CLIST  (WS_DHI + 1)

typedef __attribute__((ext_vector_type(8))) short bf16x8;
typedef __attribute__((ext_vector_type(4))) float f32x4;

__device__ __forceinline__ unsigned bf16rne(float x) {
    unsigned u = __float_as_uint(x);
    return (u + 0x7FFFu + ((u >> 16) & 1u)) >> 16;
}

// -------- K1: dictT f32 + bf16 hi/lo split + negated half-norms --------
__global__ void k_prep(const float* __restrict__ dict, float* __restrict__ ws) {
    int j = blockIdx.x, c = threadIdx.x;
    float v = dict[c * NE + j];
    ws[WS_DT + j * DIMC + c] = v;
    unsigned h = bf16rne(v);
    float fh = __uint_as_float(h << 16);
    unsigned l = bf16rne(v - fh);
    ((unsigned short*)(ws + WS_DHI))[j * DIMC + c] = (unsigned short)h;
    ((unsigned short*)(ws + WS_DLO))[j * DIMC + c] = (unsigned short)l;
    float s = v * v;
    #pragma unroll
    for (int off = 32; off > 0; off >>= 1) s += __shfl_down(s, off);
    if (c == 0) ws[WS_NORM + j] = -0.5f * s;
}

#define MFMA16(A, B, C) __builtin_amdgcn_mfma_f32_16x16x32_bf16(A, B, C, 0, 0, 0)

// -------- K2: FUSED MFMA scoring + provisional emit + partial stats --------
// 256 blocks x 512 threads (8 waves); wave computes 64 points x 512 codes.
__global__ __launch_bounds__(512, 1) void k_main(
        const float* __restrict__ x, float* __restrict__ ws,
        float* __restrict__ out, int use_part) {
    extern __shared__ float lds[];
    char*  ldsB  = (char*)lds;          // phase1: hi[512][64]bf16 | lo (128 KB)
    float* esum  = lds;                 // phase2: esum_t [c][j] 64x512 f32
    int*   lhist = (int*)(lds + 32768); // 512
    int*   bidxl = (int*)(lds + 33280); // 512
    float* lred  = lds + 33792;         // 8

    const int tid  = threadIdx.x;
    const int lane = tid & 63;
    const int w    = tid >> 6;

    const int n0 = blockIdx.x * 512 + tid;
    const int b = n0 >> 12, hw0 = n0 & 4095;
    const float* xp = x + (size_t)b * (DIMC * HWSZ) + hw0;

    // ---- load point + bf16 split + stage to LDS (chunk-XOR swizzled) ----
    float f0[DIMC];
    #pragma unroll
    for (int c = 0; c < DIMC; ++c) f0[c] = xp[c * HWSZ];
    {
        unsigned hiw[32], low[32];
        #pragma unroll
        for (int i = 0; i < 32; ++i) {
            unsigned h0 = bf16rne(f0[2 * i]);
            unsigned h1 = bf16rne(f0[2 * i + 1]);
            float fh0 = __uint_as_float(h0 << 16);
            float fh1 = __uint_as_float(h1 << 16);
            unsigned l0 = bf16rne(f0[2 * i] - fh0);
            unsigned l1 = bf16rne(f0[2 * i + 1] - fh1);
            hiw[i] = h0 | (h1 << 16);
            low[i] = l0 | (l1 << 16);
        }
        const int swz = tid & 7;
        #pragma unroll
        for (int k = 0; k < 8; ++k) {
            uint4 vh = {hiw[4 * k], hiw[4 * k + 1], hiw[4 * k + 2], hiw[4 * k + 3]};
            uint4 vl = {low[4 * k], low[4 * k + 1], low[4 * k + 2], low[4 * k + 3]};
            *(uint4*)(ldsB + tid * 128 + ((k ^ swz) << 4)) = vh;
            *(uint4*)(ldsB + 65536 + tid * 128 + ((k ^ swz) << 4)) = vl;
        }
    }
    lhist[tid] = 0;
    __syncthreads();

    // ---- A-fragments (row = lane&15, k = (lane>>4)*8 + e, +32*kk) ----
    bf16x8 ahi[4][2], alo[4][2];
    #pragma unroll
    for (int pt = 0; pt < 4; ++pt) {
        const int arow = (w << 6) + (pt << 4) + (lane & 15);
        const int swz = arow & 7;
        #pragma unroll
        for (int kk = 0; kk < 2; ++kk) {
            const int ch = (lane >> 4) + (kk << 2);
            ahi[pt][kk] = __builtin_bit_cast(bf16x8,
                *(const uint4*)(ldsB + arow * 128 + ((ch ^ swz) << 4)));
            alo[pt][kk] = __builtin_bit_cast(bf16x8,
                *(const uint4*)(ldsB + 65536 + arow * 128 + ((ch ^ swz) << 4)));
        }
    }
    __syncthreads();   // staging dead -> reuse as esum

    // zero esum region (overwrites staging)
    {
        float4 z = {0.f, 0.f, 0.f, 0.f};
        float4* e4 = (float4*)lds;
        #pragma unroll
        for (int k = 0; k < 16; ++k) e4[tid + 512 * k] = z;
    }

    // ---- MFMA sweep over 32 code-tiles ----
    const uint4* dh4 = (const uint4*)(ws + WS_DHI);
    const uint4* dl4 = (const uint4*)(ws + WS_DLO);
    const float* npl = ws + WS_NORM + (lane & 15);
    const int bl = ((lane & 15) << 3) + (lane >> 4);

    float best[4][4], sec[4][4];
    int   idx[4][4];
    #pragma unroll
    for (int pt = 0; pt < 4; ++pt)
        #pragma unroll
        for (int r = 0; r < 4; ++r) {
            best[pt][r] = -3.4e38f; sec[pt][r] = -3.4e38f; idx[pt][r] = 0;
        }

    #pragma unroll 2
    for (int jt = 0; jt < 32; ++jt) {
        uint4 uh0 = dh4[(jt << 7) + bl];
        uint4 uh1 = dh4[(jt << 7) + bl + 4];
        uint4 ul0 = dl4[(jt << 7) + bl];
        uint4 ul1 = dl4[(jt << 7) + bl + 4];
        float nrm = npl[jt << 4];
        bf16x8 bh0 = __builtin_bit_cast(bf16x8, uh0);
        bf16x8 bh1 = __builtin_bit_cast(bf16x8, uh1);
        bf16x8 bl0 = __builtin_bit_cast(bf16x8, ul0);
        bf16x8 bl1 = __builtin_bit_cast(bf16x8, ul1);
        const int jc = (jt << 4) + (lane & 15);
        #pragma unroll
        for (int pt = 0; pt < 4; ++pt) {
            f32x4 acc = {0.f, 0.f, 0.f, 0.f};
            acc = MFMA16(ahi[pt][0], bh0, acc);
            acc = MFMA16(ahi[pt][1], bh1, acc);
            acc = MFMA16(ahi[pt][0], bl0, acc);
            acc = MFMA16(ahi[pt][1], bl1, acc);
            acc = MFMA16(alo[pt][0], bh0, acc);
            acc = MFMA16(alo[pt][1], bh1, acc);
            acc = MFMA16(alo[pt][0], bl0, acc);
            acc = MFMA16(alo[pt][1], bl1, acc);
            #pragma unroll
            for (int r = 0; r < 4; ++r) {
                float s = acc[r] + nrm;
                bool gt = s > best[pt][r];
                float ns = gt ? best[pt][r] : (s > sec[pt][r] ? s : sec[pt][r]);
                best[pt][r] = gt ? s : best[pt][r];
                idx[pt][r]  = gt ? jc : idx[pt][r];
                sec[pt][r]  = ns;
            }
        }
    }

    // ---- argmax reduce across 16-lane code groups ----
    #pragma unroll
    for (int off = 8; off > 0; off >>= 1) {
        #pragma unroll
        for (int pt = 0; pt < 4; ++pt)
            #pragma unroll
            for (int r = 0; r < 4; ++r) {
                float ob = __shfl_xor(best[pt][r], off, 16);
                float os = __shfl_xor(sec[pt][r], off, 16);
                int   oi = __shfl_xor(idx[pt][r], off, 16);
                bool take = (ob > best[pt][r]) ||
                            (ob == best[pt][r] && oi < idx[pt][r]);
                float nsec = fmaxf(fminf(ob, best[pt][r]),
                                   fmaxf(os, sec[pt][r]));
                best[pt][r] = take ? ob : best[pt][r];
                idx[pt][r]  = take ? oi : idx[pt][r];
                sec[pt][r]  = nsec;
            }
    }
    if ((lane & 15) == 0) {
        const int g = lane >> 4;
        #pragma unroll
        for (int pt = 0; pt < 4; ++pt)
            #pragma unroll
            for (int r = 0; r < 4; ++r) {
                int p = (w << 6) + (pt << 4) + (g << 2) + r;
                int flag = (best[pt][r] - sec[pt][r] < MARGIN) ? 65536 : 0;
                bidxl[p] = idx[pt][r] | flag;
            }
    }
    __syncthreads();

    int ent = bidxl[tid];
    const int bi0 = ent & 511;                 // provisional winner
    ((int*)ws)[WS_BIDX + n0] = bi0;
    if (ent & 65536) {
        int pos = atomicAdd((int*)ws + WS_NFLAG, 1);
        if (pos < FCAP) ((int*)ws)[WS_FLIST + pos] = n0;
    }

    // ---- provisional emit: hist, embed_ind, quantize/out0, diff, esum ----
    atomicAdd(&lhist[bi0], 1);
    out[O2 + n0] = (float)bi0;

    const float* dptr = ws + WS_DT;
    float ssum = 0.f;
    float* o0 = out + O0 + (size_t)b * (DIMC * HWSZ) + hw0;
    const float4* q40 = (const float4*)(dptr + (size_t)bi0 * DIMC);
    #pragma unroll
    for (int c4 = 0; c4 < 16; ++c4) {
        float4 qa = q40[c4];
        const int cb = 4 * c4;
        o0[(cb + 0) * HWSZ] = qa.x;
        o0[(cb + 1) * HWSZ] = qa.y;
        o0[(cb + 2) * HWSZ] = qa.z;
        o0[(cb + 3) * HWSZ] = qa.w;
        float d;
        d = qa.x - f0[cb + 0]; ssum = fmaf(d, d, ssum);
        d = qa.y - f0[cb + 1]; ssum = fmaf(d, d, ssum);
        d = qa.z - f0[cb + 2]; ssum = fmaf(d, d, ssum);
        d = qa.w - f0[cb + 3]; ssum = fmaf(d, d, ssum);
    }

    #pragma unroll
    for (int c = 0; c < DIMC; ++c) atomicAdd(&esum[c * NE + bi0], f0[c]);
    __syncthreads();

    if (use_part) {
        float* part = ws + WS_PART + (size_t)blockIdx.x * PART_STRIDE;
        float4* p4 = (float4*)part;
        const float4* e4 = (const float4*)esum;
        #pragma unroll
        for (int k = 0; k < 16; ++k) p4[tid + 512 * k] = e4[tid + 512 * k];
        part[32768 + tid] = (float)lhist[tid];
    } else {
        #pragma unroll
        for (int k = 0; k < 64; ++k)
            atomicAdd(&ws[WS_ESUM + tid + 512 * k], esum[tid + 512 * k]);
        atomicAdd(&ws[WS_COUNTS + tid], (float)lhist[tid]);
    }

    #pragma unroll
    for (int off = 32; off > 0; off >>= 1) ssum += __shfl_down(ssum, off);
    if ((tid & 63) == 0) lred[tid >> 6] = ssum;
    __syncthreads();
    if (tid == 0) {
        float t = 0.f;
        #pragma unroll
        for (int w2 = 0; w2 < 8; ++w2) t += lred[w2];
        atomicAdd(ws + WS_DIFF, t);
    }
}

// -------- K2b: exact rescan, one wave per flagged point; log changes ----
__global__ __launch_bounds__(256, 2) void k_fix(
        const float* __restrict__ x, float* __restrict__ ws,
        float* __restrict__ out) {
    int* iw = (int*)ws;
    int nf = iw[WS_NFLAG]; if (nf > FCAP) nf = FCAP;
    const int tid = threadIdx.x;
    const int lane = tid & 63, w = tid >> 6;
    const int gw = blockIdx.x * 4 + w;
    const int nw = gridDim.x * 4;

    const float* dptr = ws + WS_DT;
    const float* nptr = ws + WS_NORM;

    for (int i = gw; i < nf; i += nw) {
        const int n = iw[WS_FLIST + i];
        const int b = n >> 12, hw = n & 4095;
        const float myf = x[(size_t)b * (DIMC * HWSZ) + (size_t)lane * HWSZ + hw];

        float bb = -3.4e38f; int bj = 0;
        #pragma unroll 2
        for (int s = 0; s < 8; ++s) {
            const int j = (lane << 3) + s;
            const float4* row = (const float4*)(dptr + (size_t)j * DIMC);
            float a0 = 0.f, a1 = 0.f, a2 = 0.f, a3 = 0.f;
            #pragma unroll
            for (int c4 = 0; c4 < 16; ++c4) {
                float4 r4 = row[c4];
                a0 = fmaf(r4.x, __shfl(myf, 4 * c4 + 0), a0);
                a1 = fmaf(r4.y, __shfl(myf, 4 * c4 + 1), a1);
                a2 = fmaf(r4.z, __shfl(myf, 4 * c4 + 2), a2);
                a3 = fmaf(r4.w, __shfl(myf, 4 * c4 + 3), a3);
            }
            float sc = ((a0 + a1) + (a2 + a3)) + nptr[j];
            if (sc > bb) { bb = sc; bj = j; }
        }
        #pragma unroll
        for (int off = 1; off < 64; off <<= 1) {
            float ob = __shfl_xor(bb, off);
            int   oi = __shfl_xor(bj, off);
            bool take = (ob > bb) || (ob == bb && oi < bj);
            bb = take ? ob : bb;
            bj = take ? oi : bj;
        }
        if (lane == 0) {
            int oldj = iw[WS_BIDX + n];
            if (bj != oldj) {
                iw[WS_BIDX + n] = bj;
                out[O2 + n] = (float)bj;
                int pos = atomicAdd(iw + WS_CHG, 1);
                if (pos < CCAP) {
                    iw[WS_CLIST + 2 * pos] = n;
                    iw[WS_CLIST + 2 * pos + 1] = oldj | (bj << 16);
                }
            }
        }
    }
}

// -------- K2d: tree-reduce per-block partials --------
__global__ void k_reduce(float* __restrict__ ws) {
    const int gid = blockIdx.x * 128 + threadIdx.x;   // [0, 8320)
    const float4* src = (const float4*)(ws + WS_PART);
    float4 acc = {0.f, 0.f, 0.f, 0.f};
    #pragma unroll 4
    for (int p = 0; p < NBLK; ++p) {
        float4 v = src[(size_t)p * (PART_STRIDE / 4) + gid];
        acc.x += v.x; acc.y += v.y; acc.z += v.z; acc.w += v.w;
    }
    ((float4*)(ws + WS_ESUM))[gid] = acc;
}

// -------- K2e: patch reduced stats/out0 for changed points (1 wave/pt) ---
__global__ __launch_bounds__(256, 2) void k_patch(
        const float* __restrict__ x, float* __restrict__ ws,
        float* __restrict__ out) {
    int* iw = (int*)ws;
    int nc = iw[WS_CHG]; if (nc > CCAP) nc = CCAP;
    const int tid = threadIdx.x;
    const int lane = tid & 63, w = tid >> 6;
    const int gw = blockIdx.x * 4 + w;
    const int nw = gridDim.x * 4;
    const float* dptr = ws + WS_DT;

    for (int i = gw; i < nc; i += nw) {
        const int n = iw[WS_CLIST + 2 * i];
        const int pk = iw[WS_CLIST + 2 * i + 1];
        const int oldj = pk & 0xFFFF, newj = pk >> 16;
        const int b = n >> 12, hw = n & 4095;
        const size_t xoff = (size_t)b * (DIMC * HWSZ) + (size_t)lane * HWSZ + hw;
        const float f = x[xoff];
        const float qn = dptr[(size_t)newj * DIMC + lane];
        const float qo = dptr[(size_t)oldj * DIMC + lane];
        out[O0 + xoff] = qn;
        float dn = qn - f, dd = qo - f;
        float delta = dn * dn - dd * dd;
        #pragma unroll
        for (int off = 32; off > 0; off >>= 1) delta += __shfl_down(delta, off);
        atomicAdd(&ws[WS_ESUM + lane * NE + newj], f);
        atomicAdd(&ws[WS_ESUM + lane * NE + oldj], -f);
        if (lane == 0) {
            atomicAdd(ws + WS_DIFF, delta);
            atomicAdd(ws + WS_COUNTS + newj, 1.0f);
            atomicAdd(ws + WS_COUNTS + oldj, -1.0f);
        }
    }
}

// -------- K3: finalize EMA buffers / outputs --------
__global__ void k_final(const float* __restrict__ ws,
                        const float* __restrict__ cluster_size,
                        const float* __restrict__ davg,
                        float* __restrict__ out) {
    __shared__ float red[16];
    __shared__ float nsh;
    const int j = threadIdx.x;

    float cnt = ws[WS_COUNTS + j];
    float ncs = DECAYF * cluster_size[j] + OMD * cnt;
    out[O3 + j] = ncs;

    float v = ncs;
    #pragma unroll
    for (int off = 32; off > 0; off >>= 1) v += __shfl_down(v, off);
    if ((j & 63) == 0) red[j >> 6] = v;
    __syncthreads();
    if (j == 0) {
        float t = 0.f;
        #pragma unroll
        for (int w = 0; w < 8; ++w) t += red[w];
        nsh = t;
    }
    __syncthreads();
    const float n = nsh;
    const float csj = (ncs + EPSF) / (n + NE * EPSF) * n;

    float asum = 0.f;
    #pragma unroll
    for (int c = 0; c < DIMC; ++c) {
        float es = ws[WS_ESUM + c * NE + j];
        float da = davg[c * NE + j];
        float nda = DECAYF * da + OMD * es;
        out[O4 + c * NE + j] = nda;
        float nd = nda / csj;
        out[O5 + c * NE + j] = nd;
        asum += fabsf(nd);
    }

    __syncthreads();
    #pragma unroll
    for (int off = 32; off > 0; off >>= 1) asum += __shfl_down(asum, off);
    if ((j & 63) == 0) red[j >> 6] = asum;
    __syncthreads();
    if (j == 0) {
        float t = 0.f;
        #pragma unroll
        for (int w = 0; w < 8; ++w) t += red[w];
        out[O6] = t / 32768.0f;
        out[O1] = ws[WS_DIFF] / 8388608.0f;
    }
}

extern "C" void kernel_launch(void* const* d_in, const int* in_sizes, int n_in,
                              void* d_out, int out_size, void* d_ws, size_t ws_size,
                              hipStream_t stream) {
    const float* x    = (const float*)d_in[0];
    const float* dict = (const float*)d_in[1];
    const float* csz  = (const float*)d_in[2];
    const float* davg = (const float*)d_in[3];
    float* out = (float*)d_out;
    float* ws  = (float*)d_ws;

    const int use_part = (ws_size >= WS_NEED_BYTES) ? 1 : 0;

    hipMemsetAsync(ws, 0, (size_t)(WS_COUNTS + 512) * sizeof(float), stream);
    hipMemsetAsync(ws + WS_NFLAG, 0, sizeof(int), stream);
    hipMemsetAsync(ws + WS_CHG, 0, sizeof(int), stream);

    k_prep<<<512, 64, 0, stream>>>(dict, ws);

    const int main_lds = 33800 * 4;
    hipFuncSetAttribute((const void*)k_main,
                        hipFuncAttributeMaxDynamicSharedMemorySize, main_lds);
    k_main<<<NBLK, 512, main_lds, stream>>>(x, ws, out, use_part);

    k_fix<<<256, 256, 0, stream>>>(x, ws, out);

    if (use_part) k_reduce<<<65, 128, 0, stream>>>(ws);

    k_patch<<<32, 256, 0, stream>>>(x, ws, out);

    k_final<<<1, 512, 0, stream>>>(ws, csz, davg, out);
}